// Round 2
// baseline (783.811 us; speedup 1.0000x reference)
//
#include <hip/hip_runtime.h>

typedef unsigned short ushort_t;
typedef unsigned int uint_t;

#define NB_AGG 2560
#define BSHIFT 7
#define BROWS 128
#define BCAP 4096   // max edges per 128-row bucket (mean 2048, sigma~45 -> 45σ safe)

__device__ __forceinline__ float bf2f(ushort_t u) {
    union { uint_t i; float f; } v; v.i = ((uint_t)u) << 16; return v.f;
}
__device__ __forceinline__ ushort_t f2bf(float f) {
    union { float f; uint_t i; } v; v.f = f;
    uint_t u = v.i;
    uint_t r = (u + 0x7fffu + ((u >> 16) & 1u)) >> 16;   // RNE
    return (ushort_t)r;
}

// ------------------------------------------------------- bucket histogram
__global__ __launch_bounds__(256) void hist_k(const int* __restrict__ dst,
                                              int* __restrict__ bh, int E, int nb) {
    __shared__ int h[1024];
    int t = threadIdx.x;
    for (int i = t; i < 1024; i += 256) h[i] = 0;
    __syncthreads();
    for (int e = blockIdx.x * 256 + t; e < E; e += gridDim.x * 256)
        atomicAdd(&h[dst[e] >> BSHIFT], 1);
    __syncthreads();
    for (int i = t; i < nb; i += 256) {
        int v = h[i];
        if (v) atomicAdd(&bh[i], v);
    }
}

// ------------------------------------------- exclusive scan of bucket sizes
// single block, 1024 threads; nb <= 1024
__global__ void bscan_k(const int* __restrict__ bh, int* __restrict__ bbase,
                        int* __restrict__ bcur, int nb, int E) {
    __shared__ int sh[1024];
    int t = threadIdx.x;
    int v = (t < nb) ? bh[t] : 0;
    sh[t] = v;
    __syncthreads();
    for (int off = 1; off < 1024; off <<= 1) {
        int u = (t >= off) ? sh[t - off] : 0;
        __syncthreads();
        sh[t] += u;
        __syncthreads();
    }
    if (t < nb) {
        int ex = sh[t] - v;
        bbase[t] = ex;
        bcur[t] = ex;
    }
    if (t == 0) bbase[nb] = E;
}

// --------------------------------------------- scatter packed recs to buckets
// rec = (src << 7) | (dst & 127); appended per bucket -> L2-merged writes
__global__ __launch_bounds__(256) void scat_k(const int* __restrict__ src,
                                              const int* __restrict__ dst,
                                              int* __restrict__ bcur,
                                              int* __restrict__ colA, int E) {
    for (int e = blockIdx.x * 256 + threadIdx.x; e < E; e += gridDim.x * 256) {
        int d = dst[e];
        int b = d >> BSHIFT;
        int pos = atomicAdd(&bcur[b], 1);
        colA[pos] = (src[e] << BSHIFT) | (d & (BROWS - 1));
    }
}

// ------------------------------- per-bucket counting sort (in place via LDS)
// emits rowp, dinv, and final colA (src ids grouped by dst row)
__global__ __launch_bounds__(256) void build_k(int* __restrict__ colA,
                                               const int* __restrict__ bbase,
                                               float* __restrict__ dinv,
                                               int* __restrict__ rowp,
                                               int N, int E) {
    __shared__ int recs[BCAP];
    __shared__ int cnt[BROWS], pfx[BROWS], cur[BROWS];
    int b = blockIdx.x, t = threadIdx.x;
    int base = bbase[b];
    int size = bbase[b + 1] - base;
    if (size > BCAP) size = BCAP;   // safety clamp (never hit for this graph)
    int row0 = b << BSHIFT;

    if (t < BROWS) { cnt[t] = 0; cur[t] = 0; }
    __syncthreads();

    for (int i = t; i < size; i += 256) {
        int r = colA[base + i];
        recs[i] = r;
        atomicAdd(&cnt[r & (BROWS - 1)], 1);
    }
    __syncthreads();

    if (t < BROWS) pfx[t] = cnt[t];
    __syncthreads();
    for (int off = 1; off < BROWS; off <<= 1) {
        int u = 0;
        if (t < BROWS && t >= off) u = pfx[t - off];
        __syncthreads();
        if (t < BROWS) pfx[t] += u;
        __syncthreads();
    }
    if (t < BROWS) {
        int row = row0 + t;
        if (row < N) {
            int ex = pfx[t] - cnt[t];
            rowp[row] = base + ex;
            dinv[row] = rsqrtf((float)cnt[t] + 1.0f);
            if (row == N - 1) rowp[N] = base + pfx[t];
        }
    }
    __syncthreads();

    for (int i = t; i < size; i += 256) {
        int r = recs[i];
        int l = r & (BROWS - 1);
        int pos = base + (pfx[l] - cnt[l]) + atomicAdd(&cur[l], 1);
        colA[pos] = r >> BSHIFT;
    }
}

// ------------------------------------------------------------- GEMM (64x64)
// One thread = one row. W staged in LDS (broadcast reads). MODE==1 applies
// folded BN (a*z+c) + ReLU to the input on the fly. Output stored bf16.
template <int MODE>
__global__ __launch_bounds__(256) void gemm_k(const float* __restrict__ Z,
                                              const float* __restrict__ W,
                                              const float* __restrict__ cA,
                                              const float* __restrict__ cC,
                                              ushort_t* __restrict__ XW, int N) {
    __shared__ float Wl[64][64];
    __shared__ float Al[64], Cl[64];
    int t = threadIdx.x;
#pragma unroll
    for (int i = 0; i < 16; ++i) {
        int idx = t + i * 256;
        Wl[idx >> 6][idx & 63] = W[idx];
    }
    if (MODE && t < 64) { Al[t] = cA[t]; Cl[t] = cC[t]; }
    __syncthreads();

    int row = blockIdx.x * 256 + t;
    if (row >= N) return;
    const float4* zr = (const float4*)(Z + (size_t)row * 64);

    float acc[64];
#pragma unroll
    for (int j = 0; j < 64; ++j) acc[j] = 0.0f;

#pragma unroll
    for (int k4 = 0; k4 < 16; ++k4) {
        float4 zv = zr[k4];
        float zz[4] = {zv.x, zv.y, zv.z, zv.w};
#pragma unroll
        for (int kk = 0; kk < 4; ++kk) {
            int k = k4 * 4 + kk;
            float z = zz[kk];
            if (MODE) {
                z = Al[k] * z + Cl[k];
                z = fmaxf(z, 0.0f);
            }
            const float4* wr = (const float4*)(&Wl[k][0]);
#pragma unroll
            for (int j4 = 0; j4 < 16; ++j4) {
                float4 w = wr[j4];
                acc[j4 * 4 + 0] += z * w.x;
                acc[j4 * 4 + 1] += z * w.y;
                acc[j4 * 4 + 2] += z * w.z;
                acc[j4 * 4 + 3] += z * w.w;
            }
        }
    }

    uint4* o = (uint4*)(XW + ((size_t)row << 6));
#pragma unroll
    for (int g8 = 0; g8 < 8; ++g8) {
        uint_t p[4];
#pragma unroll
        for (int p2 = 0; p2 < 4; ++p2) {
            float a = acc[g8 * 8 + p2 * 2 + 0];
            float b = acc[g8 * 8 + p2 * 2 + 1];
            p[p2] = (uint_t)f2bf(a) | ((uint_t)f2bf(b) << 16);
        }
        uint4 v; v.x = p[0]; v.y = p[1]; v.z = p[2]; v.w = p[3];
        o[g8] = v;
    }
}

// ------------------------------------------------- aggregation + BN partials
// One wave per row; lane = column. out[n] = dinv[n]*sum_e dinv[src]*xw[src]
//                                          + dinv[n]^2*xw[n]
__global__ __launch_bounds__(256) void agg_k(const ushort_t* __restrict__ xw,
                                             const int* __restrict__ row_ptr,
                                             const int* __restrict__ colA,
                                             const float* __restrict__ dinv,
                                             float* __restrict__ OUT,
                                             float* __restrict__ pS,
                                             float* __restrict__ pQ, int N) {
    __shared__ float ssum[64], ssq[64];
    int t = threadIdx.x, lane = t & 63, wv = t >> 6;
    if (t < 64) ssum[t] = 0.0f;
    else if (t < 128) ssq[t - 64] = 0.0f;
    __syncthreads();

    float psum = 0.0f, psq = 0.0f;

    for (int row = blockIdx.x * 4 + wv; row < N; row += NB_AGG * 4) {
        int start = row_ptr[row];
        int end = row_ptr[row + 1];
        float acc = 0.0f;
        for (int base = start; base < end; base += 64) {
            int nchunk = min(64, end - base);
            int s = 0; float dv = 0.0f;
            if (base + lane < end) {
                s = colA[base + lane];
                dv = dinv[s];
            }
            int j = 0;
            for (; j + 4 <= nchunk; j += 4) {
                int s0 = __shfl(s, j + 0), s1 = __shfl(s, j + 1);
                int s2 = __shfl(s, j + 2), s3 = __shfl(s, j + 3);
                float d0 = __shfl(dv, j + 0), d1 = __shfl(dv, j + 1);
                float d2 = __shfl(dv, j + 2), d3 = __shfl(dv, j + 3);
                ushort_t u0 = xw[(s0 << 6) | lane];
                ushort_t u1 = xw[(s1 << 6) | lane];
                ushort_t u2 = xw[(s2 << 6) | lane];
                ushort_t u3 = xw[(s3 << 6) | lane];
                acc += d0 * bf2f(u0);
                acc += d1 * bf2f(u1);
                acc += d2 * bf2f(u2);
                acc += d3 * bf2f(u3);
            }
            for (; j < nchunk; ++j) {
                int sj = __shfl(s, j);
                float dj = __shfl(dv, j);
                acc += dj * bf2f(xw[(sj << 6) | lane]);
            }
        }
        float dn = dinv[row];
        float self = bf2f(xw[(row << 6) | lane]);
        float val = dn * acc + dn * dn * self;
        OUT[(size_t)row * 64 + lane] = val;
        psum += val;
        psq += val * val;
    }

    atomicAdd(&ssum[lane], psum);
    atomicAdd(&ssq[lane], psq);
    __syncthreads();
    if (t < 64) pS[(size_t)t * NB_AGG + blockIdx.x] = ssum[t];
    else if (t < 128) pQ[(size_t)(t - 64) * NB_AGG + blockIdx.x] = ssq[t - 64];
}

// --------------------------------------------------------- BN coefficients
__global__ __launch_bounds__(256) void stats_k(const float* __restrict__ pS,
                                               const float* __restrict__ pQ,
                                               const float* __restrict__ g,
                                               const float* __restrict__ be,
                                               float* __restrict__ cA,
                                               float* __restrict__ cC, int N) {
    int c = blockIdx.x, t = threadIdx.x;
    float s = 0.0f, q = 0.0f;
    for (int i = t; i < NB_AGG; i += 256) {
        s += pS[(size_t)c * NB_AGG + i];
        q += pQ[(size_t)c * NB_AGG + i];
    }
    __shared__ float rs[256], rq[256];
    rs[t] = s; rq[t] = q;
    __syncthreads();
    for (int off = 128; off > 0; off >>= 1) {
        if (t < off) { rs[t] += rs[t + off]; rq[t] += rq[t + off]; }
        __syncthreads();
    }
    if (t == 0) {
        float mu = rs[0] / (float)N;
        float var = rq[0] / (float)N - mu * mu;
        var = fmaxf(var, 0.0f);
        float inv = rsqrtf(var + 1e-5f);
        float a = g[c] * inv;
        cA[c] = a;
        cC[c] = be[c] - mu * a;
    }
}

// ----------------------------------------------------------- final BN apply
__global__ __launch_bounds__(256) void apply_k(float* __restrict__ O,
                                               const float* __restrict__ cA,
                                               const float* __restrict__ cC,
                                               int N) {
    int total = N * 16;  // float4 count
    for (int i = blockIdx.x * 256 + threadIdx.x; i < total; i += gridDim.x * 256) {
        float4 v = ((float4*)O)[i];
        int c = (i & 15) * 4;
        v.x = cA[c + 0] * v.x + cC[c + 0];
        v.y = cA[c + 1] * v.y + cC[c + 1];
        v.z = cA[c + 2] * v.z + cC[c + 2];
        v.w = cA[c + 3] * v.w + cC[c + 3];
        ((float4*)O)[i] = v;
    }
}

// ---------------------------------------------------------------------------
extern "C" void kernel_launch(void* const* d_in, const int* in_sizes, int n_in,
                              void* d_out, int out_size, void* d_ws, size_t ws_size,
                              hipStream_t stream) {
    const float* x   = (const float*)d_in[0];
    const int*   ei  = (const int*)d_in[1];
    const float* W1  = (const float*)d_in[2];
    const float* g1  = (const float*)d_in[4];
    const float* be1 = (const float*)d_in[5];
    const float* W2  = (const float*)d_in[6];
    const float* g2  = (const float*)d_in[8];
    const float* be2 = (const float*)d_in[9];
    const float* W3  = (const float*)d_in[10];
    const float* g3  = (const float*)d_in[12];
    const float* be3 = (const float*)d_in[13];

    int N = in_sizes[0] / 64;
    int E = in_sizes[1] / 2;
    const int* srcA = ei;
    const int* dstA = ei + E;
    int nb = (N + BROWS - 1) >> BSHIFT;   // <=1024 for N<=131072

    char* w = (char*)d_ws;
    auto alloc = [&](size_t bytes) -> char* {
        char* p = w;
        w += (bytes + 255) & ~(size_t)255;
        return p;
    };
    ushort_t* xw    = (ushort_t*)alloc((size_t)N * 64 * 2);
    int*      rowp  = (int*)alloc(((size_t)N + 1) * 4);
    float*    dinv  = (float*)alloc((size_t)N * 4);
    int*      colA  = (int*)alloc((size_t)E * 4);
    int*      bh    = (int*)alloc((size_t)(nb + 1) * 4);
    int*      bbase = (int*)alloc((size_t)(nb + 1) * 4);
    int*      bcur  = (int*)alloc((size_t)nb * 4);
    float*    pS    = (float*)alloc((size_t)64 * NB_AGG * 4);
    float*    pQ    = (float*)alloc((size_t)64 * NB_AGG * 4);
    float*    cA1 = (float*)alloc(256); float* cC1 = (float*)alloc(256);
    float*    cA2 = (float*)alloc(256); float* cC2 = (float*)alloc(256);
    float*    cA3 = (float*)alloc(256); float* cC3 = (float*)alloc(256);
    (void)ws_size; (void)n_in; (void)out_size;

    float* out = (float*)d_out;

    // ---- CSR build via 782-bucket binning (once; shared by all 3 layers) ----
    hipMemsetAsync(bh, 0, (size_t)(nb + 1) * 4, stream);
    hist_k<<<256, 256, 0, stream>>>(dstA, bh, E, nb);
    bscan_k<<<1, 1024, 0, stream>>>(bh, bbase, bcur, nb, E);
    scat_k<<<1024, 256, 0, stream>>>(srcA, dstA, bcur, colA, E);
    build_k<<<nb, 256, 0, stream>>>(colA, bbase, dinv, rowp, N, E);

    int gemmGrid = (N + 255) / 256;

    // ---- layer 1 ----
    gemm_k<0><<<gemmGrid, 256, 0, stream>>>(x, W1, nullptr, nullptr, xw, N);
    agg_k<<<NB_AGG, 256, 0, stream>>>(xw, rowp, colA, dinv, out, pS, pQ, N);
    stats_k<<<64, 256, 0, stream>>>(pS, pQ, g1, be1, cA1, cC1, N);

    // ---- layer 2 ----
    gemm_k<1><<<gemmGrid, 256, 0, stream>>>(out, W2, cA1, cC1, xw, N);
    agg_k<<<NB_AGG, 256, 0, stream>>>(xw, rowp, colA, dinv, out, pS, pQ, N);
    stats_k<<<64, 256, 0, stream>>>(pS, pQ, g2, be2, cA2, cC2, N);

    // ---- layer 3 ----
    gemm_k<1><<<gemmGrid, 256, 0, stream>>>(out, W3, cA2, cC2, xw, N);
    agg_k<<<NB_AGG, 256, 0, stream>>>(xw, rowp, colA, dinv, out, pS, pQ, N);
    stats_k<<<64, 256, 0, stream>>>(pS, pQ, g3, be3, cA3, cC3, N);

    // ---- final BN (no relu) in place on d_out ----
    apply_k<<<2048, 256, 0, stream>>>(out, cA3, cC3, N);
}

// Round 3
// 425.355 us; speedup vs baseline: 1.8427x; 1.8427x over previous
//
#include <hip/hip_runtime.h>

typedef unsigned short ushort_t;
typedef unsigned int uint_t;

#define NB_AGG 2560
#define BSHIFT 7
#define BROWS 128
#define BCAP 4096    // max edges per 128-row bucket (mean 2048, ~45 sigma margin)
#define NCHUNK 256   // edge chunks for multi-split

__device__ __forceinline__ float bf2f(ushort_t u) {
    union { uint_t i; float f; } v; v.i = ((uint_t)u) << 16; return v.f;
}
__device__ __forceinline__ ushort_t f2bf(float f) {
    union { float f; uint_t i; } v; v.f = f;
    uint_t u = v.i;
    uint_t r = (u + 0x7fffu + ((u >> 16) & 1u)) >> 16;   // RNE
    return (ushort_t)r;
}

// ---------------------------------------------- multi-split: local histogram
// H[bucket * NCHUNK + chunk] = #edges of this chunk landing in bucket.
// No global atomics.
__global__ __launch_bounds__(256) void hist2_k(const int* __restrict__ dst,
                                               int* __restrict__ H, int E, int nb) {
    __shared__ int h[1024];
    int b = blockIdx.x, t = threadIdx.x;
    for (int i = t; i < nb; i += 256) h[i] = 0;
    __syncthreads();
    int per = (E + NCHUNK - 1) / NCHUNK;
    int lo = b * per, hi = min(E, lo + per);
    for (int e = lo + t; e < hi; e += 256)
        atomicAdd(&h[dst[e] >> BSHIFT], 1);
    __syncthreads();
    for (int i = t; i < nb; i += 256) H[(size_t)i * NCHUNK + b] = h[i];
}

// --------------------------- generic 3-phase exclusive scan of H (<=256K ints)
__global__ __launch_bounds__(256) void scanA_k(const int* __restrict__ v,
                                               int* __restrict__ segsum, int total) {
    int base = blockIdx.x * 1024 + threadIdx.x;
    int s = 0;
#pragma unroll
    for (int i = 0; i < 4; ++i) {
        int idx = base + i * 256;
        if (idx < total) s += v[idx];
    }
    __shared__ int sh[256];
    sh[threadIdx.x] = s;
    __syncthreads();
    for (int off = 128; off > 0; off >>= 1) {
        if (threadIdx.x < off) sh[threadIdx.x] += sh[threadIdx.x + off];
        __syncthreads();
    }
    if (threadIdx.x == 0) segsum[blockIdx.x] = sh[0];
}

// exclusive scan of <=256 segment sums, single block of 256 threads
__global__ void scanB_k(int* segsum, int nseg) {
    __shared__ int sh[256];
    int t = threadIdx.x;
    int own = (t < nseg) ? segsum[t] : 0;
    sh[t] = own;
    __syncthreads();
    for (int off = 1; off < 256; off <<= 1) {
        int v = (t >= off) ? sh[t - off] : 0;
        __syncthreads();
        sh[t] += v;
        __syncthreads();
    }
    if (t < nseg) segsum[t] = sh[t] - own;
}

// in-place exclusive scan of each 1024-segment, offset by segsum
__global__ __launch_bounds__(256) void scanC2_k(int* __restrict__ H,
                                                const int* __restrict__ segsum,
                                                int total) {
    int t = threadIdx.x;
    int base = blockIdx.x * 1024 + t * 4;
    int c0 = 0, c1 = 0, c2 = 0, c3 = 0;
    if (base + 0 < total) c0 = H[base + 0];
    if (base + 1 < total) c1 = H[base + 1];
    if (base + 2 < total) c2 = H[base + 2];
    if (base + 3 < total) c3 = H[base + 3];
    int tsum = c0 + c1 + c2 + c3;
    __shared__ int sh[256];
    sh[t] = tsum;
    __syncthreads();
    for (int off = 1; off < 256; off <<= 1) {
        int v = (t >= off) ? sh[t - off] : 0;
        __syncthreads();
        sh[t] += v;
        __syncthreads();
    }
    int excl = segsum[blockIdx.x] + sh[t] - tsum;
    if (base + 0 < total) H[base + 0] = excl;
    if (base + 1 < total) H[base + 1] = excl + c0;
    if (base + 2 < total) H[base + 2] = excl + c0 + c1;
    if (base + 3 < total) H[base + 3] = excl + c0 + c1 + c2;
}

// ------------------------------ scatter packed recs using LDS-only cursors
// rec = (src << 7) | (dst & 127). Each (bucket,chunk) region is contiguous;
// neighbor chunks' regions adjoin -> L2-merged writes, no global atomics.
__global__ __launch_bounds__(256) void scat2_k(const int* __restrict__ src,
                                               const int* __restrict__ dst,
                                               const int* __restrict__ H,
                                               int* __restrict__ colA, int E, int nb) {
    __shared__ int cur[1024];
    int b = blockIdx.x, t = threadIdx.x;
    for (int i = t; i < nb; i += 256) cur[i] = H[(size_t)i * NCHUNK + b];
    __syncthreads();
    int per = (E + NCHUNK - 1) / NCHUNK;
    int lo = b * per, hi = min(E, lo + per);
    for (int e = lo + t; e < hi; e += 256) {
        int d = dst[e];
        int bk = d >> BSHIFT;
        int pos = atomicAdd(&cur[bk], 1);   // LDS atomic
        colA[pos] = (src[e] << BSHIFT) | (d & (BROWS - 1));
    }
}

// ------------------------------- per-bucket counting sort (in place via LDS)
// emits rowp, dinv, and final colA (src ids grouped by dst row)
__global__ __launch_bounds__(256) void build_k(int* __restrict__ colA,
                                               const int* __restrict__ H,
                                               float* __restrict__ dinv,
                                               int* __restrict__ rowp,
                                               int N, int E, int nb) {
    __shared__ int recs[BCAP];
    __shared__ int cnt[BROWS], pfx[BROWS], cur[BROWS];
    int b = blockIdx.x, t = threadIdx.x;
    int base = H[(size_t)b * NCHUNK];
    int next = (b + 1 < nb) ? H[(size_t)(b + 1) * NCHUNK] : E;
    int size = next - base;
    if (size > BCAP) size = BCAP;   // safety clamp (never hit for this graph)
    int row0 = b << BSHIFT;

    if (t < BROWS) { cnt[t] = 0; cur[t] = 0; }
    __syncthreads();

    for (int i = t; i < size; i += 256) {
        int r = colA[base + i];
        recs[i] = r;
        atomicAdd(&cnt[r & (BROWS - 1)], 1);
    }
    __syncthreads();

    if (t < BROWS) pfx[t] = cnt[t];
    __syncthreads();
    for (int off = 1; off < BROWS; off <<= 1) {
        int u = 0;
        if (t < BROWS && t >= off) u = pfx[t - off];
        __syncthreads();
        if (t < BROWS) pfx[t] += u;
        __syncthreads();
    }
    if (t < BROWS) {
        int row = row0 + t;
        if (row < N) {
            int ex = pfx[t] - cnt[t];
            rowp[row] = base + ex;
            dinv[row] = rsqrtf((float)cnt[t] + 1.0f);
            if (row == N - 1) rowp[N] = base + pfx[t];
        }
    }
    __syncthreads();

    for (int i = t; i < size; i += 256) {
        int r = recs[i];
        int l = r & (BROWS - 1);
        int pos = base + (pfx[l] - cnt[l]) + atomicAdd(&cur[l], 1);
        colA[pos] = r >> BSHIFT;
    }
}

// ------------------------------------------------------------- GEMM (64x64)
// One thread = one row. W staged in LDS (broadcast reads). MODE==1 applies
// folded BN (a*z+c) + ReLU to the input on the fly. Output stored bf16.
template <int MODE>
__global__ __launch_bounds__(256) void gemm_k(const float* __restrict__ Z,
                                              const float* __restrict__ W,
                                              const float* __restrict__ cA,
                                              const float* __restrict__ cC,
                                              ushort_t* __restrict__ XW, int N) {
    __shared__ float Wl[64][64];
    __shared__ float Al[64], Cl[64];
    int t = threadIdx.x;
#pragma unroll
    for (int i = 0; i < 16; ++i) {
        int idx = t + i * 256;
        Wl[idx >> 6][idx & 63] = W[idx];
    }
    if (MODE && t < 64) { Al[t] = cA[t]; Cl[t] = cC[t]; }
    __syncthreads();

    int row = blockIdx.x * 256 + t;
    if (row >= N) return;
    const float4* zr = (const float4*)(Z + (size_t)row * 64);

    float acc[64];
#pragma unroll
    for (int j = 0; j < 64; ++j) acc[j] = 0.0f;

#pragma unroll
    for (int k4 = 0; k4 < 16; ++k4) {
        float4 zv = zr[k4];
        float zz[4] = {zv.x, zv.y, zv.z, zv.w};
#pragma unroll
        for (int kk = 0; kk < 4; ++kk) {
            int k = k4 * 4 + kk;
            float z = zz[kk];
            if (MODE) {
                z = Al[k] * z + Cl[k];
                z = fmaxf(z, 0.0f);
            }
            const float4* wr = (const float4*)(&Wl[k][0]);
#pragma unroll
            for (int j4 = 0; j4 < 16; ++j4) {
                float4 w = wr[j4];
                acc[j4 * 4 + 0] += z * w.x;
                acc[j4 * 4 + 1] += z * w.y;
                acc[j4 * 4 + 2] += z * w.z;
                acc[j4 * 4 + 3] += z * w.w;
            }
        }
    }

    uint4* o = (uint4*)(XW + ((size_t)row << 6));
#pragma unroll
    for (int g8 = 0; g8 < 8; ++g8) {
        uint_t p[4];
#pragma unroll
        for (int p2 = 0; p2 < 4; ++p2) {
            float a = acc[g8 * 8 + p2 * 2 + 0];
            float b = acc[g8 * 8 + p2 * 2 + 1];
            p[p2] = (uint_t)f2bf(a) | ((uint_t)f2bf(b) << 16);
        }
        uint4 v; v.x = p[0]; v.y = p[1]; v.z = p[2]; v.w = p[3];
        o[g8] = v;
    }
}

// ------------------------------------------------- aggregation + BN partials
// One wave per row; lane = column. out[n] = dinv[n]*sum_e dinv[src]*xw[src]
//                                          + dinv[n]^2*xw[n]
__global__ __launch_bounds__(256) void agg_k(const ushort_t* __restrict__ xw,
                                             const int* __restrict__ row_ptr,
                                             const int* __restrict__ colA,
                                             const float* __restrict__ dinv,
                                             float* __restrict__ OUT,
                                             float* __restrict__ pS,
                                             float* __restrict__ pQ, int N) {
    __shared__ float ssum[64], ssq[64];
    int t = threadIdx.x, lane = t & 63, wv = t >> 6;
    if (t < 64) ssum[t] = 0.0f;
    else if (t < 128) ssq[t - 64] = 0.0f;
    __syncthreads();

    float psum = 0.0f, psq = 0.0f;

    for (int row = blockIdx.x * 4 + wv; row < N; row += NB_AGG * 4) {
        int start = row_ptr[row];
        int end = row_ptr[row + 1];
        float acc = 0.0f;
        for (int base = start; base < end; base += 64) {
            int nchunk = min(64, end - base);
            int s = 0; float dv = 0.0f;
            if (base + lane < end) {
                s = colA[base + lane];
                dv = dinv[s];
            }
            int j = 0;
            for (; j + 4 <= nchunk; j += 4) {
                int s0 = __shfl(s, j + 0), s1 = __shfl(s, j + 1);
                int s2 = __shfl(s, j + 2), s3 = __shfl(s, j + 3);
                float d0 = __shfl(dv, j + 0), d1 = __shfl(dv, j + 1);
                float d2 = __shfl(dv, j + 2), d3 = __shfl(dv, j + 3);
                ushort_t u0 = xw[(s0 << 6) | lane];
                ushort_t u1 = xw[(s1 << 6) | lane];
                ushort_t u2 = xw[(s2 << 6) | lane];
                ushort_t u3 = xw[(s3 << 6) | lane];
                acc += d0 * bf2f(u0);
                acc += d1 * bf2f(u1);
                acc += d2 * bf2f(u2);
                acc += d3 * bf2f(u3);
            }
            for (; j < nchunk; ++j) {
                int sj = __shfl(s, j);
                float dj = __shfl(dv, j);
                acc += dj * bf2f(xw[(sj << 6) | lane]);
            }
        }
        float dn = dinv[row];
        float self = bf2f(xw[(row << 6) | lane]);
        float val = dn * acc + dn * dn * self;
        OUT[(size_t)row * 64 + lane] = val;
        psum += val;
        psq += val * val;
    }

    atomicAdd(&ssum[lane], psum);
    atomicAdd(&ssq[lane], psq);
    __syncthreads();
    if (t < 64) pS[(size_t)t * NB_AGG + blockIdx.x] = ssum[t];
    else if (t < 128) pQ[(size_t)(t - 64) * NB_AGG + blockIdx.x] = ssq[t - 64];
}

// --------------------------------------------------------- BN coefficients
__global__ __launch_bounds__(256) void stats_k(const float* __restrict__ pS,
                                               const float* __restrict__ pQ,
                                               const float* __restrict__ g,
                                               const float* __restrict__ be,
                                               float* __restrict__ cA,
                                               float* __restrict__ cC, int N) {
    int c = blockIdx.x, t = threadIdx.x;
    float s = 0.0f, q = 0.0f;
    for (int i = t; i < NB_AGG; i += 256) {
        s += pS[(size_t)c * NB_AGG + i];
        q += pQ[(size_t)c * NB_AGG + i];
    }
    __shared__ float rs[256], rq[256];
    rs[t] = s; rq[t] = q;
    __syncthreads();
    for (int off = 128; off > 0; off >>= 1) {
        if (t < off) { rs[t] += rs[t + off]; rq[t] += rq[t + off]; }
        __syncthreads();
    }
    if (t == 0) {
        float mu = rs[0] / (float)N;
        float var = rq[0] / (float)N - mu * mu;
        var = fmaxf(var, 0.0f);
        float inv = rsqrtf(var + 1e-5f);
        float a = g[c] * inv;
        cA[c] = a;
        cC[c] = be[c] - mu * a;
    }
}

// ----------------------------------------------------------- final BN apply
__global__ __launch_bounds__(256) void apply_k(float* __restrict__ O,
                                               const float* __restrict__ cA,
                                               const float* __restrict__ cC,
                                               int N) {
    int total = N * 16;  // float4 count
    for (int i = blockIdx.x * 256 + threadIdx.x; i < total; i += gridDim.x * 256) {
        float4 v = ((float4*)O)[i];
        int c = (i & 15) * 4;
        v.x = cA[c + 0] * v.x + cC[c + 0];
        v.y = cA[c + 1] * v.y + cC[c + 1];
        v.z = cA[c + 2] * v.z + cC[c + 2];
        v.w = cA[c + 3] * v.w + cC[c + 3];
        ((float4*)O)[i] = v;
    }
}

// ---------------------------------------------------------------------------
extern "C" void kernel_launch(void* const* d_in, const int* in_sizes, int n_in,
                              void* d_out, int out_size, void* d_ws, size_t ws_size,
                              hipStream_t stream) {
    const float* x   = (const float*)d_in[0];
    const int*   ei  = (const int*)d_in[1];
    const float* W1  = (const float*)d_in[2];
    const float* g1  = (const float*)d_in[4];
    const float* be1 = (const float*)d_in[5];
    const float* W2  = (const float*)d_in[6];
    const float* g2  = (const float*)d_in[8];
    const float* be2 = (const float*)d_in[9];
    const float* W3  = (const float*)d_in[10];
    const float* g3  = (const float*)d_in[12];
    const float* be3 = (const float*)d_in[13];

    int N = in_sizes[0] / 64;
    int E = in_sizes[1] / 2;
    const int* srcA = ei;
    const int* dstA = ei + E;
    int nb = (N + BROWS - 1) >> BSHIFT;          // <=1024 for N<=131072
    int total = nb * NCHUNK;                     // multi-split matrix size
    int nseg = (total + 1023) / 1024;            // <=256

    char* w = (char*)d_ws;
    auto alloc = [&](size_t bytes) -> char* {
        char* p = w;
        w += (bytes + 255) & ~(size_t)255;
        return p;
    };
    ushort_t* xw    = (ushort_t*)alloc((size_t)N * 64 * 2);
    int*      rowp  = (int*)alloc(((size_t)N + 1) * 4);
    float*    dinv  = (float*)alloc((size_t)N * 4);
    int*      colA  = (int*)alloc((size_t)E * 4);
    int*      H     = (int*)alloc((size_t)total * 4);
    int*      segsum= (int*)alloc((size_t)nseg * 4);
    float*    pS    = (float*)alloc((size_t)64 * NB_AGG * 4);
    float*    pQ    = (float*)alloc((size_t)64 * NB_AGG * 4);
    float*    cA1 = (float*)alloc(256); float* cC1 = (float*)alloc(256);
    float*    cA2 = (float*)alloc(256); float* cC2 = (float*)alloc(256);
    float*    cA3 = (float*)alloc(256); float* cC3 = (float*)alloc(256);
    (void)ws_size; (void)n_in; (void)out_size;

    float* out = (float*)d_out;

    // ---- CSR build via atomic-free multi-split (once; shared by 3 layers) ----
    hist2_k<<<NCHUNK, 256, 0, stream>>>(dstA, H, E, nb);
    scanA_k<<<nseg, 256, 0, stream>>>(H, segsum, total);
    scanB_k<<<1, 256, 0, stream>>>(segsum, nseg);
    scanC2_k<<<nseg, 256, 0, stream>>>(H, segsum, total);
    scat2_k<<<NCHUNK, 256, 0, stream>>>(srcA, dstA, H, colA, E, nb);
    build_k<<<nb, 256, 0, stream>>>(colA, H, dinv, rowp, N, E, nb);

    int gemmGrid = (N + 255) / 256;

    // ---- layer 1 ----
    gemm_k<0><<<gemmGrid, 256, 0, stream>>>(x, W1, nullptr, nullptr, xw, N);
    agg_k<<<NB_AGG, 256, 0, stream>>>(xw, rowp, colA, dinv, out, pS, pQ, N);
    stats_k<<<64, 256, 0, stream>>>(pS, pQ, g1, be1, cA1, cC1, N);

    // ---- layer 2 ----
    gemm_k<1><<<gemmGrid, 256, 0, stream>>>(out, W2, cA1, cC1, xw, N);
    agg_k<<<NB_AGG, 256, 0, stream>>>(xw, rowp, colA, dinv, out, pS, pQ, N);
    stats_k<<<64, 256, 0, stream>>>(pS, pQ, g2, be2, cA2, cC2, N);

    // ---- layer 3 ----
    gemm_k<1><<<gemmGrid, 256, 0, stream>>>(out, W3, cA2, cC2, xw, N);
    agg_k<<<NB_AGG, 256, 0, stream>>>(xw, rowp, colA, dinv, out, pS, pQ, N);
    stats_k<<<64, 256, 0, stream>>>(pS, pQ, g3, be3, cA3, cC3, N);

    // ---- final BN (no relu) in place on d_out ----
    apply_k<<<2048, 256, 0, stream>>>(out, cA3, cC3, N);
}

// Round 4
// 389.110 us; speedup vs baseline: 2.0144x; 1.0931x over previous
//
#include <hip/hip_runtime.h>

typedef unsigned short ushort_t;
typedef unsigned int uint_t;

#define NB_AGG 2560
#define BSHIFT 7
#define BROWS 128
#define BCAP 4096    // max edges per 128-row bucket (mean 2048, ~45 sigma margin)
#define NCHUNK 256   // edge chunks for multi-split

__device__ __forceinline__ float bf2f(ushort_t u) {
    union { uint_t i; float f; } v; v.i = ((uint_t)u) << 16; return v.f;
}
__device__ __forceinline__ ushort_t f2bf(float f) {
    union { float f; uint_t i; } v; v.f = f;
    uint_t u = v.i;
    uint_t r = (u + 0x7fffu + ((u >> 16) & 1u)) >> 16;   // RNE
    return (ushort_t)r;
}

// ---------------------------------------------- multi-split: local histogram
__global__ __launch_bounds__(256) void hist2_k(const int* __restrict__ dst,
                                               int* __restrict__ H, int E, int nb) {
    __shared__ int h[1024];
    int b = blockIdx.x, t = threadIdx.x;
    for (int i = t; i < nb; i += 256) h[i] = 0;
    __syncthreads();
    int per = (E + NCHUNK - 1) / NCHUNK;
    int lo = b * per, hi = min(E, lo + per);
    for (int e = lo + t; e < hi; e += 256)
        atomicAdd(&h[dst[e] >> BSHIFT], 1);
    __syncthreads();
    for (int i = t; i < nb; i += 256) H[(size_t)i * NCHUNK + b] = h[i];
}

// --------------------------- generic 3-phase exclusive scan of H (<=256K ints)
__global__ __launch_bounds__(256) void scanA_k(const int* __restrict__ v,
                                               int* __restrict__ segsum, int total) {
    int base = blockIdx.x * 1024 + threadIdx.x;
    int s = 0;
#pragma unroll
    for (int i = 0; i < 4; ++i) {
        int idx = base + i * 256;
        if (idx < total) s += v[idx];
    }
    __shared__ int sh[256];
    sh[threadIdx.x] = s;
    __syncthreads();
    for (int off = 128; off > 0; off >>= 1) {
        if (threadIdx.x < off) sh[threadIdx.x] += sh[threadIdx.x + off];
        __syncthreads();
    }
    if (threadIdx.x == 0) segsum[blockIdx.x] = sh[0];
}

__global__ void scanB_k(int* segsum, int nseg) {
    __shared__ int sh[256];
    int t = threadIdx.x;
    int own = (t < nseg) ? segsum[t] : 0;
    sh[t] = own;
    __syncthreads();
    for (int off = 1; off < 256; off <<= 1) {
        int v = (t >= off) ? sh[t - off] : 0;
        __syncthreads();
        sh[t] += v;
        __syncthreads();
    }
    if (t < nseg) segsum[t] = sh[t] - own;
}

__global__ __launch_bounds__(256) void scanC2_k(int* __restrict__ H,
                                                const int* __restrict__ segsum,
                                                int total) {
    int t = threadIdx.x;
    int base = blockIdx.x * 1024 + t * 4;
    int c0 = 0, c1 = 0, c2 = 0, c3 = 0;
    if (base + 0 < total) c0 = H[base + 0];
    if (base + 1 < total) c1 = H[base + 1];
    if (base + 2 < total) c2 = H[base + 2];
    if (base + 3 < total) c3 = H[base + 3];
    int tsum = c0 + c1 + c2 + c3;
    __shared__ int sh[256];
    sh[t] = tsum;
    __syncthreads();
    for (int off = 1; off < 256; off <<= 1) {
        int v = (t >= off) ? sh[t - off] : 0;
        __syncthreads();
        sh[t] += v;
        __syncthreads();
    }
    int excl = segsum[blockIdx.x] + sh[t] - tsum;
    if (base + 0 < total) H[base + 0] = excl;
    if (base + 1 < total) H[base + 1] = excl + c0;
    if (base + 2 < total) H[base + 2] = excl + c0 + c1;
    if (base + 3 < total) H[base + 3] = excl + c0 + c1 + c2;
}

// ------------------------------ scatter packed recs using LDS-only cursors
__global__ __launch_bounds__(256) void scat2_k(const int* __restrict__ src,
                                               const int* __restrict__ dst,
                                               const int* __restrict__ H,
                                               int* __restrict__ colA, int E, int nb) {
    __shared__ int cur[1024];
    int b = blockIdx.x, t = threadIdx.x;
    for (int i = t; i < nb; i += 256) cur[i] = H[(size_t)i * NCHUNK + b];
    __syncthreads();
    int per = (E + NCHUNK - 1) / NCHUNK;
    int lo = b * per, hi = min(E, lo + per);
    for (int e = lo + t; e < hi; e += 256) {
        int d = dst[e];
        int bk = d >> BSHIFT;
        int pos = atomicAdd(&cur[bk], 1);   // LDS atomic
        colA[pos] = (src[e] << BSHIFT) | (d & (BROWS - 1));
    }
}

// ------------------------------- per-bucket counting sort (in place via LDS)
__global__ __launch_bounds__(256) void build_k(int* __restrict__ colA,
                                               const int* __restrict__ H,
                                               float* __restrict__ dinv,
                                               int* __restrict__ rowp,
                                               int N, int E, int nb) {
    __shared__ int recs[BCAP];
    __shared__ int cnt[BROWS], pfx[BROWS], cur[BROWS];
    int b = blockIdx.x, t = threadIdx.x;
    int base = H[(size_t)b * NCHUNK];
    int next = (b + 1 < nb) ? H[(size_t)(b + 1) * NCHUNK] : E;
    int size = next - base;
    if (size > BCAP) size = BCAP;   // safety clamp (never hit for this graph)
    int row0 = b << BSHIFT;

    if (t < BROWS) { cnt[t] = 0; cur[t] = 0; }
    __syncthreads();

    for (int i = t; i < size; i += 256) {
        int r = colA[base + i];
        recs[i] = r;
        atomicAdd(&cnt[r & (BROWS - 1)], 1);
    }
    __syncthreads();

    if (t < BROWS) pfx[t] = cnt[t];
    __syncthreads();
    for (int off = 1; off < BROWS; off <<= 1) {
        int u = 0;
        if (t < BROWS && t >= off) u = pfx[t - off];
        __syncthreads();
        if (t < BROWS) pfx[t] += u;
        __syncthreads();
    }
    if (t < BROWS) {
        int row = row0 + t;
        if (row < N) {
            int ex = pfx[t] - cnt[t];
            rowp[row] = base + ex;
            dinv[row] = rsqrtf((float)cnt[t] + 1.0f);
            if (row == N - 1) rowp[N] = base + pfx[t];
        }
    }
    __syncthreads();

    for (int i = t; i < size; i += 256) {
        int r = recs[i];
        int l = r & (BROWS - 1);
        int pos = base + (pfx[l] - cnt[l]) + atomicAdd(&cur[l], 1);
        colA[pos] = r >> BSHIFT;
    }
}

// ------------------------------------------------------------- GEMM (64x64)
template <int MODE>
__global__ __launch_bounds__(256) void gemm_k(const float* __restrict__ Z,
                                              const float* __restrict__ W,
                                              const float* __restrict__ cA,
                                              const float* __restrict__ cC,
                                              ushort_t* __restrict__ XW, int N) {
    __shared__ float Wl[64][64];
    __shared__ float Al[64], Cl[64];
    int t = threadIdx.x;
#pragma unroll
    for (int i = 0; i < 16; ++i) {
        int idx = t + i * 256;
        Wl[idx >> 6][idx & 63] = W[idx];
    }
    if (MODE && t < 64) { Al[t] = cA[t]; Cl[t] = cC[t]; }
    __syncthreads();

    int row = blockIdx.x * 256 + t;
    if (row >= N) return;
    const float4* zr = (const float4*)(Z + (size_t)row * 64);

    float acc[64];
#pragma unroll
    for (int j = 0; j < 64; ++j) acc[j] = 0.0f;

#pragma unroll
    for (int k4 = 0; k4 < 16; ++k4) {
        float4 zv = zr[k4];
        float zz[4] = {zv.x, zv.y, zv.z, zv.w};
#pragma unroll
        for (int kk = 0; kk < 4; ++kk) {
            int k = k4 * 4 + kk;
            float z = zz[kk];
            if (MODE) {
                z = Al[k] * z + Cl[k];
                z = fmaxf(z, 0.0f);
            }
            const float4* wr = (const float4*)(&Wl[k][0]);
#pragma unroll
            for (int j4 = 0; j4 < 16; ++j4) {
                float4 w = wr[j4];
                acc[j4 * 4 + 0] += z * w.x;
                acc[j4 * 4 + 1] += z * w.y;
                acc[j4 * 4 + 2] += z * w.z;
                acc[j4 * 4 + 3] += z * w.w;
            }
        }
    }

    uint4* o = (uint4*)(XW + ((size_t)row << 6));
#pragma unroll
    for (int g8 = 0; g8 < 8; ++g8) {
        uint_t p[4];
#pragma unroll
        for (int p2 = 0; p2 < 4; ++p2) {
            float a = acc[g8 * 8 + p2 * 2 + 0];
            float b = acc[g8 * 8 + p2 * 2 + 1];
            p[p2] = (uint_t)f2bf(a) | ((uint_t)f2bf(b) << 16);
        }
        uint4 v; v.x = p[0]; v.y = p[1]; v.z = p[2]; v.w = p[3];
        o[g8] = v;
    }
}

// ------------------------------------------------- aggregation + BN partials
// Wave layout: g = lane>>4 (edge group 0..3), c = lane&15 (column quad).
// Each load instruction gathers 4 edges x 8B = 4 cache lines; unroll 8 ->
// up to 32 lines in flight per wave. No shuffles in the hot loop.
__global__ __launch_bounds__(256) void agg_k(const ushort_t* __restrict__ xw,
                                             const int* __restrict__ row_ptr,
                                             const int* __restrict__ colA,
                                             const float* __restrict__ dinv,
                                             float* __restrict__ OUT,
                                             float* __restrict__ pS,
                                             float* __restrict__ pQ, int N) {
    __shared__ float ssum[64], ssq[64];
    int t = threadIdx.x, lane = t & 63, wv = t >> 6;
    int g = lane >> 4;      // edge-in-group
    int c = lane & 15;      // column quad (cols 4c..4c+3)
    if (t < 64) ssum[t] = 0.0f;
    else if (t < 128) ssq[t - 64] = 0.0f;
    __syncthreads();

    const uint2* xw2 = (const uint2*)xw;
    float ps0 = 0, ps1 = 0, ps2 = 0, ps3 = 0;
    float pq0 = 0, pq1 = 0, pq2 = 0, pq3 = 0;

    for (int row = blockIdx.x * 4 + wv; row < N; row += NB_AGG * 4) {
        int start = row_ptr[row];
        int end = row_ptr[row + 1];
        float a0 = 0, a1 = 0, a2 = 0, a3 = 0;

        for (int base = start; base < end; base += 32) {
            int sA[8];
            float dA[8];
#pragma unroll
            for (int u = 0; u < 8; ++u) {
                int e = base + u * 4 + g;
                int ec = min(e, end - 1);          // clamp to row's own edges
                sA[u] = colA[ec];                  // 16-lane broadcast load
                sA[u] = (e < end) ? sA[u] : (sA[u] | 0x40000000);  // mark invalid
            }
#pragma unroll
            for (int u = 0; u < 8; ++u) {
                int s = sA[u] & 0x3fffffff;
                dA[u] = (sA[u] & 0x40000000) ? 0.0f : dinv[s];
            }
#pragma unroll
            for (int u = 0; u < 8; ++u) {
                int s = sA[u] & 0x3fffffff;
                uint2 v = xw2[(size_t)s * 16 + c];
                float d = dA[u];
                a0 += d * bf2f((ushort_t)(v.x & 0xffffu));
                a1 += d * bf2f((ushort_t)(v.x >> 16));
                a2 += d * bf2f((ushort_t)(v.y & 0xffffu));
                a3 += d * bf2f((ushort_t)(v.y >> 16));
            }
        }

        // reduce across the 4 edge groups (lanes differing in bits 4,5)
        a0 += __shfl_xor(a0, 16); a0 += __shfl_xor(a0, 32);
        a1 += __shfl_xor(a1, 16); a1 += __shfl_xor(a1, 32);
        a2 += __shfl_xor(a2, 16); a2 += __shfl_xor(a2, 32);
        a3 += __shfl_xor(a3, 16); a3 += __shfl_xor(a3, 32);

        float dn = dinv[row];
        float dn2 = dn * dn;
        uint2 sv = xw2[(size_t)row * 16 + c];
        float v0 = dn * a0 + dn2 * bf2f((ushort_t)(sv.x & 0xffffu));
        float v1 = dn * a1 + dn2 * bf2f((ushort_t)(sv.x >> 16));
        float v2 = dn * a2 + dn2 * bf2f((ushort_t)(sv.y & 0xffffu));
        float v3 = dn * a3 + dn2 * bf2f((ushort_t)(sv.y >> 16));

        if (g == 0) {
            float4 o; o.x = v0; o.y = v1; o.z = v2; o.w = v3;
            *(float4*)(OUT + (size_t)row * 64 + c * 4) = o;
            ps0 += v0; ps1 += v1; ps2 += v2; ps3 += v3;
            pq0 += v0 * v0; pq1 += v1 * v1; pq2 += v2 * v2; pq3 += v3 * v3;
        }
    }

    if (g == 0) {
        atomicAdd(&ssum[c * 4 + 0], ps0); atomicAdd(&ssq[c * 4 + 0], pq0);
        atomicAdd(&ssum[c * 4 + 1], ps1); atomicAdd(&ssq[c * 4 + 1], pq1);
        atomicAdd(&ssum[c * 4 + 2], ps2); atomicAdd(&ssq[c * 4 + 2], pq2);
        atomicAdd(&ssum[c * 4 + 3], ps3); atomicAdd(&ssq[c * 4 + 3], pq3);
    }
    __syncthreads();
    if (t < 64) pS[(size_t)t * NB_AGG + blockIdx.x] = ssum[t];
    else if (t < 128) pQ[(size_t)(t - 64) * NB_AGG + blockIdx.x] = ssq[t - 64];
}

// --------------------------------------------------------- BN coefficients
__global__ __launch_bounds__(256) void stats_k(const float* __restrict__ pS,
                                               const float* __restrict__ pQ,
                                               const float* __restrict__ g,
                                               const float* __restrict__ be,
                                               float* __restrict__ cA,
                                               float* __restrict__ cC, int N) {
    int c = blockIdx.x, t = threadIdx.x;
    float s = 0.0f, q = 0.0f;
    for (int i = t; i < NB_AGG; i += 256) {
        s += pS[(size_t)c * NB_AGG + i];
        q += pQ[(size_t)c * NB_AGG + i];
    }
    __shared__ float rs[256], rq[256];
    rs[t] = s; rq[t] = q;
    __syncthreads();
    for (int off = 128; off > 0; off >>= 1) {
        if (t < off) { rs[t] += rs[t + off]; rq[t] += rq[t + off]; }
        __syncthreads();
    }
    if (t == 0) {
        float mu = rs[0] / (float)N;
        float var = rq[0] / (float)N - mu * mu;
        var = fmaxf(var, 0.0f);
        float inv = rsqrtf(var + 1e-5f);
        float a = g[c] * inv;
        cA[c] = a;
        cC[c] = be[c] - mu * a;
    }
}

// ----------------------------------------------------------- final BN apply
__global__ __launch_bounds__(256) void apply_k(float* __restrict__ O,
                                               const float* __restrict__ cA,
                                               const float* __restrict__ cC,
                                               int N) {
    int total = N * 16;  // float4 count
    for (int i = blockIdx.x * 256 + threadIdx.x; i < total; i += gridDim.x * 256) {
        float4 v = ((float4*)O)[i];
        int c = (i & 15) * 4;
        v.x = cA[c + 0] * v.x + cC[c + 0];
        v.y = cA[c + 1] * v.y + cC[c + 1];
        v.z = cA[c + 2] * v.z + cC[c + 2];
        v.w = cA[c + 3] * v.w + cC[c + 3];
        ((float4*)O)[i] = v;
    }
}

// ---------------------------------------------------------------------------
extern "C" void kernel_launch(void* const* d_in, const int* in_sizes, int n_in,
                              void* d_out, int out_size, void* d_ws, size_t ws_size,
                              hipStream_t stream) {
    const float* x   = (const float*)d_in[0];
    const int*   ei  = (const int*)d_in[1];
    const float* W1  = (const float*)d_in[2];
    const float* g1  = (const float*)d_in[4];
    const float* be1 = (const float*)d_in[5];
    const float* W2  = (const float*)d_in[6];
    const float* g2  = (const float*)d_in[8];
    const float* be2 = (const float*)d_in[9];
    const float* W3  = (const float*)d_in[10];
    const float* g3  = (const float*)d_in[12];
    const float* be3 = (const float*)d_in[13];

    int N = in_sizes[0] / 64;
    int E = in_sizes[1] / 2;
    const int* srcA = ei;
    const int* dstA = ei + E;
    int nb = (N + BROWS - 1) >> BSHIFT;          // <=1024 for N<=131072
    int total = nb * NCHUNK;                     // multi-split matrix size
    int nseg = (total + 1023) / 1024;            // <=256

    char* w = (char*)d_ws;
    auto alloc = [&](size_t bytes) -> char* {
        char* p = w;
        w += (bytes + 255) & ~(size_t)255;
        return p;
    };
    ushort_t* xw    = (ushort_t*)alloc((size_t)N * 64 * 2);
    int*      rowp  = (int*)alloc(((size_t)N + 1) * 4);
    float*    dinv  = (float*)alloc((size_t)N * 4);
    int*      colA  = (int*)alloc((size_t)E * 4);
    int*      H     = (int*)alloc((size_t)total * 4);
    int*      segsum= (int*)alloc((size_t)nseg * 4);
    float*    pS    = (float*)alloc((size_t)64 * NB_AGG * 4);
    float*    pQ    = (float*)alloc((size_t)64 * NB_AGG * 4);
    float*    cA1 = (float*)alloc(256); float* cC1 = (float*)alloc(256);
    float*    cA2 = (float*)alloc(256); float* cC2 = (float*)alloc(256);
    float*    cA3 = (float*)alloc(256); float* cC3 = (float*)alloc(256);
    (void)ws_size; (void)n_in; (void)out_size;

    float* out = (float*)d_out;

    // ---- CSR build via atomic-free multi-split (once; shared by 3 layers) ----
    hist2_k<<<NCHUNK, 256, 0, stream>>>(dstA, H, E, nb);
    scanA_k<<<nseg, 256, 0, stream>>>(H, segsum, total);
    scanB_k<<<1, 256, 0, stream>>>(segsum, nseg);
    scanC2_k<<<nseg, 256, 0, stream>>>(H, segsum, total);
    scat2_k<<<NCHUNK, 256, 0, stream>>>(srcA, dstA, H, colA, E, nb);
    build_k<<<nb, 256, 0, stream>>>(colA, H, dinv, rowp, N, E, nb);

    int gemmGrid = (N + 255) / 256;

    // ---- layer 1 ----
    gemm_k<0><<<gemmGrid, 256, 0, stream>>>(x, W1, nullptr, nullptr, xw, N);
    agg_k<<<NB_AGG, 256, 0, stream>>>(xw, rowp, colA, dinv, out, pS, pQ, N);
    stats_k<<<64, 256, 0, stream>>>(pS, pQ, g1, be1, cA1, cC1, N);

    // ---- layer 2 ----
    gemm_k<1><<<gemmGrid, 256, 0, stream>>>(out, W2, cA1, cC1, xw, N);
    agg_k<<<NB_AGG, 256, 0, stream>>>(xw, rowp, colA, dinv, out, pS, pQ, N);
    stats_k<<<64, 256, 0, stream>>>(pS, pQ, g2, be2, cA2, cC2, N);

    // ---- layer 3 ----
    gemm_k<1><<<gemmGrid, 256, 0, stream>>>(out, W3, cA2, cC2, xw, N);
    agg_k<<<NB_AGG, 256, 0, stream>>>(xw, rowp, colA, dinv, out, pS, pQ, N);
    stats_k<<<64, 256, 0, stream>>>(pS, pQ, g3, be3, cA3, cC3, N);

    // ---- final BN (no relu) in place on d_out ----
    apply_k<<<2048, 256, 0, stream>>>(out, cA3, cC3, N);
}